// Round 18
// baseline (81.074 us; speedup 1.0000x reference)
//
#include <hip/hip_runtime.h>
#include <math.h>

#define Q 8192      // B*E query rows
#define O 8192      // codebook entries
#define CDIM 256    // channels
#define BM 128      // rows per block
#define TN 64       // cols per tile (B tile = 64 x 256 fp16 = 32 KB, x2 dbuf)
#define NSPLIT 8
#define TILES 16    // (O/NSPLIT)/TN

typedef _Float16 half_t;
typedef _Float16 h8 __attribute__((ext_vector_type(8)));
typedef _Float16 h4 __attribute__((ext_vector_type(4)));
typedef float f32x4 __attribute__((ext_vector_type(4)));
typedef unsigned long long u64;

// ---------------- threefry2x32 (JAX key(42), partitionable) ----------------

__device__ __forceinline__ unsigned rotl32(unsigned x, int r) {
    return (x << r) | (x >> (32 - r));
}

__device__ __forceinline__ float bits_to_normal(unsigned bits) {
    float f = __uint_as_float((bits >> 9) | 0x3f800000u) - 1.0f;
    const float lo = -0.99999994f;
    float u = fmaxf(lo, f * 2.0f + lo);
    float w = -log1pf(-(u * u));
    float p;
    if (w < 5.0f) {
        w = w - 2.5f;
        p = 2.81022636e-08f;
        p = fmaf(p, w, 3.43273939e-07f);
        p = fmaf(p, w, -3.5233877e-06f);
        p = fmaf(p, w, -4.39150654e-06f);
        p = fmaf(p, w, 0.00021858087f);
        p = fmaf(p, w, -0.00125372503f);
        p = fmaf(p, w, -0.00417768164f);
        p = fmaf(p, w, 0.246640727f);
        p = fmaf(p, w, 1.50140941f);
    } else {
        w = sqrtf(w) - 3.0f;
        p = -0.000200214257f;
        p = fmaf(p, w, 0.000100950558f);
        p = fmaf(p, w, 0.00134934322f);
        p = fmaf(p, w, -0.00367342844f);
        p = fmaf(p, w, 0.00573950773f);
        p = fmaf(p, w, -0.0076224613f);
        p = fmaf(p, w, 0.00943887047f);
        p = fmaf(p, w, 1.00167406f);
        p = fmaf(p, w, 2.83297682f);
    }
    return 1.41421356f * (p * u);
}

__device__ __forceinline__ float decode_std(const unsigned* p) {
    unsigned w0 = p[0];
    float f = __uint_as_float(w0);
    float af = fabsf(f);
    if (af >= 1e-8f && af <= 1e8f) return f;
    if (w0 != 0u && w0 < (1u << 23)) return (float)w0;
    unsigned w1 = p[1];
    double d = __longlong_as_double(((unsigned long long)w1 << 32) | (unsigned long long)w0);
    double ad = fabs(d);
    if (ad >= 1e-8 && ad <= 1e8) return (float)d;
    return 0.0f;
}

__device__ __forceinline__ int noise_for_row(int i, const unsigned* nstd) {
    const unsigned k0 = 0u, k1 = 42u;
    const unsigned k2 = 0x1BD11BDAu ^ k0 ^ k1;
    unsigned x0 = 0u + k0;
    unsigned x1 = (unsigned)i + k1;
#define TF_R(r) { x0 += x1; x1 = rotl32(x1, r); x1 ^= x0; }
    TF_R(13) TF_R(15) TF_R(26) TF_R(6)   x0 += k1; x1 += k2 + 1u;
    TF_R(17) TF_R(29) TF_R(16) TF_R(24)  x0 += k2; x1 += k0 + 2u;
    TF_R(13) TF_R(15) TF_R(26) TF_R(6)   x0 += k0; x1 += k1 + 3u;
    TF_R(17) TF_R(29) TF_R(16) TF_R(24)  x0 += k1; x1 += k2 + 4u;
    TF_R(13) TF_R(15) TF_R(26) TF_R(6)   x0 += k2; x1 += k0 + 5u;
#undef TF_R
    unsigned bits = x0 ^ x1;   // partitionable 32-bit draw: bits1 ^ bits2
    float ns = decode_std(nstd);
    return (int)rintf(ns * bits_to_normal(bits));
}

// -------- prep: cbnorm (exact f32) + fp16 codebook mirror, one pass ---------

__global__ void k_prep(const float* __restrict__ cb, float* __restrict__ cbnorm,
                       half_t* __restrict__ CBh) {
    int wv = threadIdx.x >> 6, lane = threadIdx.x & 63;
    int row = blockIdx.x * 4 + wv;
    float4 v = *(const float4*)(cb + (size_t)row * CDIM + lane * 4);
    float s = v.x * v.x + v.y * v.y + v.z * v.z + v.w * v.w;
    #pragma unroll
    for (int off = 32; off; off >>= 1) s += __shfl_down(s, off);
    if (lane == 0) cbnorm[row] = s;
    h4 hv = {(half_t)v.x, (half_t)v.y, (half_t)v.z, (half_t)v.w};
    *(h4*)(CBh + (size_t)row * CDIM + lane * 4) = hv;
}

// legacy cbnorm (fallback path only)
__global__ void k_cbnorm(const float* __restrict__ cb, float* __restrict__ cbnorm) {
    int wv = threadIdx.x >> 6, lane = threadIdx.x & 63;
    int row = blockIdx.x * 4 + wv;
    float4 v = *(const float4*)(cb + (size_t)row * CDIM + lane * 4);
    float s = v.x * v.x + v.y * v.y + v.z * v.z + v.w * v.w;
    #pragma unroll
    for (int off = 32; off; off >>= 1) s += __shfl_down(s, off);
    if (lane == 0) cbnorm[row] = s;
}

// ---------------- packed-key top-2 (branch-free) ----------------

__device__ __forceinline__ u64 pack_key(float s, int col) {
    unsigned b = __float_as_uint(s);
    unsigned o = b ^ (((unsigned)((int)b >> 31)) | 0x80000000u);  // monotone map
    return ((u64)o << 32) | (unsigned)col;
}
__device__ __forceinline__ u64 umin64(u64 a, u64 b) { return a < b ? a : b; }
__device__ __forceinline__ u64 umax64(u64 a, u64 b) { return a < b ? b : a; }

// scalar top-2 insert (fallback kernel only)
__device__ __forceinline__ void ins2(float v, int idx, float& b1, int& i1, float& b2, int& i2) {
    if (v < b1 || (v == b1 && idx < i1)) { b2 = b1; i2 = i1; b1 = v; i1 = idx; }
    else if (v < b2 || (v == b2 && idx < i2)) { b2 = v; i2 = idx; }
}

// ---------------- MFMA fp16 distance GEMM + per-split top-2 ----------------
// Round-18: r17 math (absmax 0) + T3/T14 double-buffered async staging:
// BN->64, 16 tiles, 2x32KB LDS ping-pong (same 64KB total -> same occupancy).
// Tile t+1's 8 global loads are issued into NAMED stage regs (rule #20)
// BEFORE tile t's compute; ds_write happens after the post-compute barrier.
// L2 latency hides under the 8 K-steps. Same totals: 4 B-reads : 8 MFMA.
#define MFMA16(a, b, c) __builtin_amdgcn_mfma_f32_16x16x32_f16(a, b, c, 0, 0, 0)
#define FOR8(M) M(0) M(1) M(2) M(3) M(4) M(5) M(6) M(7)
#define FOR4(M) M(0) M(1) M(2) M(3)

__launch_bounds__(256, 2)
__global__ void k_argmin_mfma(const float* __restrict__ X, const half_t* __restrict__ CBh,
                              const float* __restrict__ cbnorm,
                              u64* __restrict__ P1, u64* __restrict__ P2) {
    __shared__ __align__(16) half_t LBS[2 * TN * CDIM];   // 2 x 32 KB

    const int tid = threadIdx.x;
    const int l = tid & 63, w = tid >> 6;              // 4 waves
    const int l15 = l & 15, g = l >> 4, l7 = l & 7;
    const int rowTile = blockIdx.x * BM;
    const int split = blockIdx.y;
    const int colSplit = split * (O / NSPLIT);         // 1024-wide column stripe

    // ---- A prologue: 16 named h8 frags (2 bands x 8 ksteps), fp16(-2x) ----
    const float* xr0 = X + (size_t)(rowTile + w * 32 + l15) * CDIM + g * 8;
    const float* xr1 = xr0 + 16 * CDIM;
#define DECL_A(ks) h8 a0_##ks, a1_##ks;
    FOR8(DECL_A)
#undef DECL_A
#define LOADA(ks) { \
        float4 u0 = *(const float4*)(xr0 + (ks) * 32); \
        float4 u1 = *(const float4*)(xr0 + (ks) * 32 + 4); \
        a0_##ks = (h8){(half_t)(-2.f*u0.x), (half_t)(-2.f*u0.y), (half_t)(-2.f*u0.z), (half_t)(-2.f*u0.w), \
                       (half_t)(-2.f*u1.x), (half_t)(-2.f*u1.y), (half_t)(-2.f*u1.z), (half_t)(-2.f*u1.w)}; \
        float4 v0 = *(const float4*)(xr1 + (ks) * 32); \
        float4 v1 = *(const float4*)(xr1 + (ks) * 32 + 4); \
        a1_##ks = (h8){(half_t)(-2.f*v0.x), (half_t)(-2.f*v0.y), (half_t)(-2.f*v0.z), (half_t)(-2.f*v0.w), \
                       (half_t)(-2.f*v1.x), (half_t)(-2.f*v1.y), (half_t)(-2.f*v1.z), (half_t)(-2.f*v1.w)}; }
    FOR8(LOADA)
#undef LOADA

    // ---- staging lane indices + named stage registers (8 chunks/thread) ----
#define DECL_STAGE(p) \
    const int srow##p = ((p) * 256 + tid) >> 5; \
    const int sdst##p = srow##p * 256 + (((p) * 256 + tid) & 31) * 8; \
    const half_t* ssrc##p = CBh + (size_t)(colSplit + srow##p) * CDIM \
                          + (((((p) * 256 + tid) & 31)) ^ (srow##p & 7)) * 8; \
    h8 sg##p;
    FOR8(DECL_STAGE)
#undef DECL_STAGE
#define LOADSTAGE(t_) { \
    sg0 = *(const h8*)(ssrc0 + (t_) * (TN * CDIM)); \
    sg1 = *(const h8*)(ssrc1 + (t_) * (TN * CDIM)); \
    sg2 = *(const h8*)(ssrc2 + (t_) * (TN * CDIM)); \
    sg3 = *(const h8*)(ssrc3 + (t_) * (TN * CDIM)); \
    sg4 = *(const h8*)(ssrc4 + (t_) * (TN * CDIM)); \
    sg5 = *(const h8*)(ssrc5 + (t_) * (TN * CDIM)); \
    sg6 = *(const h8*)(ssrc6 + (t_) * (TN * CDIM)); \
    sg7 = *(const h8*)(ssrc7 + (t_) * (TN * CDIM)); }
#define WRITESTAGE(bufp) { \
    *(h8*)((bufp) + sdst0) = sg0; \
    *(h8*)((bufp) + sdst1) = sg1; \
    *(h8*)((bufp) + sdst2) = sg2; \
    *(h8*)((bufp) + sdst3) = sg3; \
    *(h8*)((bufp) + sdst4) = sg4; \
    *(h8*)((bufp) + sdst5) = sg5; \
    *(h8*)((bufp) + sdst6) = sg6; \
    *(h8*)((bufp) + sdst7) = sg7; }

    // ---- top-2 state: 8 slots (2 bands x 4 regs) x 2 packed u64 ----
#define DECL_SLOT(s) u64 m1_##s = ~0ULL, m2_##s = ~0ULL;
    FOR8(DECL_SLOT)
#undef DECL_SLOT

#define DECL_ACC(fj) f32x4 cA##fj, cB##fj;
    FOR4(DECL_ACC)
#undef DECL_ACC

    // prologue: stage tile 0 into buf 0
    LOADSTAGE(0)
    WRITESTAGE(LBS)
    __syncthreads();

    for (int t = 0; t < TILES; ++t) {
        const int colBase = colSplit + t * TN;
        const half_t* bufc = LBS + (t & 1) * (TN * CDIM);

        if (t < TILES - 1) LOADSTAGE(t + 1)   // async: no wait until WRITESTAGE

        // acc init = ||c||^2
#define INIT_ACC(fj) { \
            float cn_ = cbnorm[colBase + (fj) * 16 + l15]; \
            cA##fj = (f32x4){cn_, cn_, cn_, cn_}; \
            cB##fj = (f32x4){cn_, cn_, cn_, cn_}; }
        FOR4(INIT_ACC)
#undef INIT_ACC

        // ---- 8 K-steps: A from regs, B from LDS buf[t&1] ----
#define KSTEP(ks) { \
        const int koff = ((((ks) * 4 + g) ^ l7) * 8); \
        const half_t* bp = bufc + l15 * 256 + koff; \
        h8 b0 = *(const h8*)(bp + 0 * 4096); \
        h8 b1 = *(const h8*)(bp + 1 * 4096); \
        h8 b2 = *(const h8*)(bp + 2 * 4096); \
        h8 b3 = *(const h8*)(bp + 3 * 4096); \
        cA0 = MFMA16(a0_##ks, b0, cA0); cB0 = MFMA16(a1_##ks, b0, cB0); \
        cA1 = MFMA16(a0_##ks, b1, cA1); cB1 = MFMA16(a1_##ks, b1, cB1); \
        cA2 = MFMA16(a0_##ks, b2, cA2); cB2 = MFMA16(a1_##ks, b2, cB2); \
        cA3 = MFMA16(a0_##ks, b3, cA3); cB3 = MFMA16(a1_##ks, b3, cB3); }
        FOR8(KSTEP)
#undef KSTEP

        // ---- epilogue: branch-free packed top-2 insert ----
#define INS(val, col, s) { \
            u64 k_ = pack_key((val), (col)); \
            u64 lo_ = umin64(m1_##s, k_); \
            u64 hi_ = umax64(m1_##s, k_); \
            m1_##s = lo_; m2_##s = umin64(m2_##s, hi_); }
#define EPI(fj) { \
            int col = colBase + (fj) * 16 + l15; \
            INS(cA##fj[0], col, 0) \
            INS(cA##fj[1], col, 1) \
            INS(cA##fj[2], col, 2) \
            INS(cA##fj[3], col, 3) \
            INS(cB##fj[0], col, 4) \
            INS(cB##fj[1], col, 5) \
            INS(cB##fj[2], col, 6) \
            INS(cB##fj[3], col, 7) }
        FOR4(EPI)
#undef EPI
#undef INS

        if (t < TILES - 1) {
            __syncthreads();   // all waves done reading buf[(t+1)&1] (tile t-1)
            WRITESTAGE(LBS + ((t + 1) & 1) * (TN * CDIM))
            __syncthreads();   // next tile's buffer visible
        }
    }

    // ---- butterfly across the 16 lanes sharing each output row ----
#define BFLY_STEP(s, m) { \
        u64 o1 = __shfl_xor(m1_##s, m); \
        u64 o2 = __shfl_xor(m2_##s, m); \
        u64 lo_ = umin64(m1_##s, o1); \
        u64 hi_ = umax64(m1_##s, o1); \
        m1_##s = lo_; \
        m2_##s = umin64(umin64(m2_##s, o2), hi_); }
#define BFLY(s) BFLY_STEP(s, 1) BFLY_STEP(s, 2) BFLY_STEP(s, 4) BFLY_STEP(s, 8)
    FOR8(BFLY)
#undef BFLY
#undef BFLY_STEP

#define STORE(s) if (l15 == (s)) { \
        int row = rowTile + w * 32 + ((s) >> 2) * 16 + g * 4 + ((s) & 3); \
        P1[row * NSPLIT + split] = m1_##s; \
        P2[row * NSPLIT + split] = m2_##s; }
    FOR8(STORE)
#undef STORE
}

// ---------------- f32 fallback (used only if ws too small) ------------------

__launch_bounds__(256, 2)
__global__ void k_argmin_f32(const float* __restrict__ X, const float* __restrict__ CB,
                             const float* __restrict__ cbnorm,
                             u64* __restrict__ P1, u64* __restrict__ P2) {
    __shared__ float LBUF[2 * 32 * (BM + 4)];
    float (*Fl)[BM + 4] = (float (*)[BM + 4])LBUF;
    float (*Cl)[BM + 4] = (float (*)[BM + 4])(LBUF + 32 * (BM + 4));

    const int tid = threadIdx.x;
    const int tx = tid & 15, ty = tid >> 4;
    const int rowTile = blockIdx.x * BM;
    const int split = blockIdx.y;
    const int lr = tid >> 3;
    const int lk = (tid & 7) * 4;

    float b1[8], b2[8];
    int i1[8], i2[8];
    #pragma unroll
    for (int i = 0; i < 8; ++i) { b1[i] = 3.4e38f; b2[i] = 3.4e38f; i1[i] = 0; i2[i] = 0; }

    for (int t = 0; t < (O / NSPLIT) / BM; ++t) {
        const int colBase = split * (O / NSPLIT) + t * BM;
        float acc[8][8];
        #pragma unroll
        for (int i = 0; i < 8; ++i)
            #pragma unroll
            for (int j = 0; j < 8; ++j) acc[i][j] = 0.0f;

        for (int k0 = 0; k0 < CDIM; k0 += 32) {
            __syncthreads();
            #pragma unroll
            for (int p = 0; p < 4; ++p) {
                int r = lr + p * 32;
                float4 v = *(const float4*)(X + (size_t)(rowTile + r) * CDIM + k0 + lk);
                Fl[lk + 0][r] = v.x; Fl[lk + 1][r] = v.y;
                Fl[lk + 2][r] = v.z; Fl[lk + 3][r] = v.w;
                float4 c = *(const float4*)(CB + (size_t)(colBase + r) * CDIM + k0 + lk);
                Cl[lk + 0][r] = c.x; Cl[lk + 1][r] = c.y;
                Cl[lk + 2][r] = c.z; Cl[lk + 3][r] = c.w;
            }
            __syncthreads();
            #pragma unroll
            for (int kk = 0; kk < 32; ++kk) {
                float4 a0 = *(const float4*)&Fl[kk][ty * 4];
                float4 a1 = *(const float4*)&Fl[kk][64 + ty * 4];
                float4 c0 = *(const float4*)&Cl[kk][tx * 4];
                float4 c1 = *(const float4*)&Cl[kk][64 + tx * 4];
                float a[8] = {a0.x, a0.y, a0.z, a0.w, a1.x, a1.y, a1.z, a1.w};
                float b[8] = {c0.x, c0.y, c0.z, c0.w, c1.x, c1.y, c1.z, c1.w};
                #pragma unroll
                for (int i = 0; i < 8; ++i)
                    #pragma unroll
                    for (int j = 0; j < 8; ++j)
                        acc[i][j] = fmaf(a[i], b[j], acc[i][j]);
            }
        }
        #pragma unroll
        for (int j = 0; j < 8; ++j) {
            int col = colBase + ((j < 4) ? (tx * 4 + j) : (64 + tx * 4 + (j - 4)));
            float cn = cbnorm[col];
            #pragma unroll
            for (int i = 0; i < 8; ++i) {
                float sc = fmaf(-2.0f, acc[i][j], cn);
                ins2(sc, col, b1[i], i1[i], b2[i], i2[i]);
            }
        }
    }

    __syncthreads();
    float* R1v = LBUF;
    int*   R1i = (int*)(LBUF + 2048);
    float* R2v = LBUF + 4096;
    int*   R2i = (int*)(LBUF + 6144);
    #pragma unroll
    for (int i = 0; i < 8; ++i) {
        int r = (i < 4) ? (ty * 4 + i) : (64 + ty * 4 + (i - 4));
        R1v[r * 16 + tx] = b1[i]; R1i[r * 16 + tx] = i1[i];
        R2v[r * 16 + tx] = b2[i]; R2i[r * 16 + tx] = i2[i];
    }
    __syncthreads();
    if (tid < BM) {
        float g1 = 3.4e38f, g2 = 3.4e38f; int gi1 = 0, gi2 = 0;
        #pragma unroll
        for (int x = 0; x < 16; ++x) {
            ins2(R1v[tid * 16 + x], R1i[tid * 16 + x], g1, gi1, g2, gi2);
            ins2(R2v[tid * 16 + x], R2i[tid * 16 + x], g1, gi1, g2, gi2);
        }
        int row = rowTile + tid;
        P1[row * NSPLIT + split] = pack_key(g1, gi1);
        P2[row * NSPLIT + split] = pack_key(g2, gi2);
    }
}

// -------- final: one wave per row. packed split-merge, f64 rescue (||x||^2
// cancels), inline threefry noise, gather, out write, combined loss partial.

__global__ void k_final(const float* __restrict__ X, const float* __restrict__ Y,
                        const float* __restrict__ CB,
                        const u64* __restrict__ P1, const u64* __restrict__ P2,
                        const unsigned* __restrict__ nstd,
                        float* __restrict__ out, float* __restrict__ s) {
    const int wv = threadIdx.x >> 6, lane = threadIdx.x & 63;
    const int row = blockIdx.x * 4 + wv;

    u64 k1 = ~0ULL, k2 = ~0ULL;
    #pragma unroll
    for (int sp = 0; sp < NSPLIT; ++sp) {
        u64 q1 = P1[row * NSPLIT + sp];
        u64 q2 = P2[row * NSPLIT + sp];
        u64 lo = umin64(k1, q1);
        u64 hi = umax64(k1, q1);
        k1 = lo;
        k2 = umin64(umin64(k2, q2), hi);
    }
    int gi1 = (int)(k1 & 0xFFFFFFFFu);
    int gi2 = (int)(k2 & 0xFFFFFFFFu);

    const float4 xv = *(const float4*)(X + (size_t)row * CDIM + lane * 4);
    const float4 yv = *(const float4*)(Y + (size_t)row * CDIM + lane * 4);
    const float4 c1v = *(const float4*)(CB + (size_t)gi1 * CDIM + lane * 4);
    const float4 c2v = *(const float4*)(CB + (size_t)gi2 * CDIM + lane * 4);

    double u1 = (double)c1v.x * ((double)c1v.x - 2.0 * (double)xv.x)
              + (double)c1v.y * ((double)c1v.y - 2.0 * (double)xv.y)
              + (double)c1v.z * ((double)c1v.z - 2.0 * (double)xv.z)
              + (double)c1v.w * ((double)c1v.w - 2.0 * (double)xv.w);
    double u2 = (double)c2v.x * ((double)c2v.x - 2.0 * (double)xv.x)
              + (double)c2v.y * ((double)c2v.y - 2.0 * (double)xv.y)
              + (double)c2v.z * ((double)c2v.z - 2.0 * (double)xv.z)
              + (double)c2v.w * ((double)c2v.w - 2.0 * (double)xv.w);
    #pragma unroll
    for (int m = 32; m; m >>= 1) {
        u1 += __shfl_xor(u1, m);
        u2 += __shfl_xor(u2, m);
    }
    int indDet = (u2 < u1 || (u2 == u1 && gi2 < gi1)) ? gi2 : gi1;
    int indNoisy = min(max(indDet + noise_for_row(row, nstd), 0), O - 1);

    float4 qd;
    qd.x = (indDet == gi1) ? c1v.x : c2v.x;
    qd.y = (indDet == gi1) ? c1v.y : c2v.y;
    qd.z = (indDet == gi1) ? c1v.z : c2v.z;
    qd.w = (indDet == gi1) ? c1v.w : c2v.w;
    const float4 qn = *(const float4*)(CB + (size_t)indNoisy * CDIM + lane * 4);

    float4 o;
    o.x = xv.x + (qn.x - xv.x);
    o.y = xv.y + (qn.y - xv.y);
    o.z = xv.z + (qn.z - xv.z);
    o.w = xv.w + (qn.w - xv.w);
    *(float4*)(out + (size_t)row * CDIM + lane * 4) = o;

    float e = 0.0f;
    {
        float d1, d2, d3;
        d1 = o.x - yv.x; d2 = xv.x - qd.x; d3 = qn.x - xv.x;
        e += d1 * d1 + 0.25f * (d2 * d2) + d3 * d3;
        d1 = o.y - yv.y; d2 = xv.y - qd.y; d3 = qn.y - xv.y;
        e += d1 * d1 + 0.25f * (d2 * d2) + d3 * d3;
        d1 = o.z - yv.z; d2 = xv.z - qd.z; d3 = qn.z - xv.z;
        e += d1 * d1 + 0.25f * (d2 * d2) + d3 * d3;
        d1 = o.w - yv.w; d2 = xv.w - qd.w; d3 = qn.w - xv.w;
        e += d1 * d1 + 0.25f * (d2 * d2) + d3 * d3;
    }
    #pragma unroll
    for (int m = 32; m; m >>= 1) e += __shfl_xor(e, m);
    if (lane == 0) s[row] = e;
}

__global__ void k_loss(const float* __restrict__ s, float* __restrict__ loss_out) {
    double a = 0.0;
    const float4* s4 = (const float4*)s;
    #pragma unroll
    for (int k = 0; k < 8; ++k) {
        float4 v = s4[threadIdx.x + k * 256];
        a += (double)v.x + (double)v.y + (double)v.z + (double)v.w;
    }
    #pragma unroll
    for (int off = 32; off; off >>= 1) a += __shfl_down(a, off);
    __shared__ double sh[4];
    int lane = threadIdx.x & 63, wv = threadIdx.x >> 6;
    if (lane == 0) sh[wv] = a;
    __syncthreads();
    if (threadIdx.x == 0) {
        double A = sh[0] + sh[1] + sh[2] + sh[3];
        loss_out[0] = (float)(A / ((double)Q * (double)CDIM));
    }
}

extern "C" void kernel_launch(void* const* d_in, const int* in_sizes, int n_in,
                              void* d_out, int out_size, void* d_ws, size_t ws_size,
                              hipStream_t stream) {
    int si = -1;
    const void* bigs[3] = {nullptr, nullptr, nullptr};
    int nb = 0;
    for (int i = 0; i < n_in; ++i) {
        if (in_sizes[i] == 1 && si < 0) si = i;
        else if (nb < 3) bigs[nb++] = d_in[i];
    }
    const float*    X    = (const float*)bigs[0];
    const float*    Y    = (const float*)bigs[1];
    const float*    CB   = (const float*)bigs[2];
    const unsigned* NSTD = (const unsigned*)(si >= 0 ? d_in[si] : d_in[n_in - 1]);
    float* out = (float*)d_out;

    float* ws = (float*)d_ws;
    float*  cbnorm = ws;                         // 8192 f32
    float*  s      = ws + 8192;                  // 8192 f32
    u64*    P1     = (u64*)(ws + 16384);         // 8192*8 u64
    u64*    P2     = (u64*)(ws + 147456);
    half_t* CBh    = (half_t*)(ws + 278528);     // 2M halfs = 4 MB
    const size_t WS_NEEDED = (size_t)(278528 + 1048576) * 4;  // 5,308,416 B

    if (ws_size >= WS_NEEDED) {
        hipLaunchKernelGGL(k_prep, dim3(O / 4), dim3(256), 0, stream, CB, cbnorm, CBh);
        hipLaunchKernelGGL(k_argmin_mfma, dim3(Q / BM, NSPLIT), dim3(256), 0, stream,
                           X, CBh, cbnorm, P1, P2);
    } else {
        hipLaunchKernelGGL(k_cbnorm, dim3(O / 4), dim3(256), 0, stream, CB, cbnorm);
        hipLaunchKernelGGL(k_argmin_f32, dim3(Q / BM, NSPLIT), dim3(256), 0, stream,
                           X, CB, cbnorm, P1, P2);
    }

    hipLaunchKernelGGL(k_final, dim3(Q / 4), dim3(256), 0, stream,
                       X, Y, CB, P1, P2, NSTD, out, s);
    hipLaunchKernelGGL(k_loss, dim3(1), dim3(256), 0, stream, s, out + (size_t)Q * CDIM);
}

// Round 19
// 74.354 us; speedup vs baseline: 1.0904x; 1.0904x over previous
//
#include <hip/hip_runtime.h>
#include <math.h>

#define Q 8192      // B*E query rows
#define O 8192      // codebook entries
#define CDIM 256    // channels
#define BM 128      // rows per block
#define BN 128      // cols per tile (LDS B tile = 128 x 256 fp16 = 64 KB)
#define NSPLIT 8
#define TILES 8     // (O/NSPLIT)/BN

typedef _Float16 half_t;
typedef _Float16 h8 __attribute__((ext_vector_type(8)));
typedef _Float16 h4 __attribute__((ext_vector_type(4)));
typedef float f32x4 __attribute__((ext_vector_type(4)));
typedef unsigned long long u64;

// ---------------- threefry2x32 (JAX key(42), partitionable) ----------------

__device__ __forceinline__ unsigned rotl32(unsigned x, int r) {
    return (x << r) | (x >> (32 - r));
}

__device__ __forceinline__ float bits_to_normal(unsigned bits) {
    float f = __uint_as_float((bits >> 9) | 0x3f800000u) - 1.0f;
    const float lo = -0.99999994f;
    float u = fmaxf(lo, f * 2.0f + lo);
    float w = -log1pf(-(u * u));
    float p;
    if (w < 5.0f) {
        w = w - 2.5f;
        p = 2.81022636e-08f;
        p = fmaf(p, w, 3.43273939e-07f);
        p = fmaf(p, w, -3.5233877e-06f);
        p = fmaf(p, w, -4.39150654e-06f);
        p = fmaf(p, w, 0.00021858087f);
        p = fmaf(p, w, -0.00125372503f);
        p = fmaf(p, w, -0.00417768164f);
        p = fmaf(p, w, 0.246640727f);
        p = fmaf(p, w, 1.50140941f);
    } else {
        w = sqrtf(w) - 3.0f;
        p = -0.000200214257f;
        p = fmaf(p, w, 0.000100950558f);
        p = fmaf(p, w, 0.00134934322f);
        p = fmaf(p, w, -0.00367342844f);
        p = fmaf(p, w, 0.00573950773f);
        p = fmaf(p, w, -0.0076224613f);
        p = fmaf(p, w, 0.00943887047f);
        p = fmaf(p, w, 1.00167406f);
        p = fmaf(p, w, 2.83297682f);
    }
    return 1.41421356f * (p * u);
}

__device__ __forceinline__ float decode_std(const unsigned* p) {
    unsigned w0 = p[0];
    float f = __uint_as_float(w0);
    float af = fabsf(f);
    if (af >= 1e-8f && af <= 1e8f) return f;
    if (w0 != 0u && w0 < (1u << 23)) return (float)w0;
    unsigned w1 = p[1];
    double d = __longlong_as_double(((unsigned long long)w1 << 32) | (unsigned long long)w0);
    double ad = fabs(d);
    if (ad >= 1e-8 && ad <= 1e8) return (float)d;
    return 0.0f;
}

__device__ __forceinline__ int noise_for_row(int i, const unsigned* nstd) {
    const unsigned k0 = 0u, k1 = 42u;
    const unsigned k2 = 0x1BD11BDAu ^ k0 ^ k1;
    unsigned x0 = 0u + k0;
    unsigned x1 = (unsigned)i + k1;
#define TF_R(r) { x0 += x1; x1 = rotl32(x1, r); x1 ^= x0; }
    TF_R(13) TF_R(15) TF_R(26) TF_R(6)   x0 += k1; x1 += k2 + 1u;
    TF_R(17) TF_R(29) TF_R(16) TF_R(24)  x0 += k2; x1 += k0 + 2u;
    TF_R(13) TF_R(15) TF_R(26) TF_R(6)   x0 += k0; x1 += k1 + 3u;
    TF_R(17) TF_R(29) TF_R(16) TF_R(24)  x0 += k1; x1 += k2 + 4u;
    TF_R(13) TF_R(15) TF_R(26) TF_R(6)   x0 += k2; x1 += k0 + 5u;
#undef TF_R
    unsigned bits = x0 ^ x1;   // partitionable 32-bit draw: bits1 ^ bits2
    float ns = decode_std(nstd);
    return (int)rintf(ns * bits_to_normal(bits));
}

// -------- prep: cbnorm (exact f32) + fp16 codebook mirror, one pass ---------

__global__ void k_prep(const float* __restrict__ cb, float* __restrict__ cbnorm,
                       half_t* __restrict__ CBh) {
    int wv = threadIdx.x >> 6, lane = threadIdx.x & 63;
    int row = blockIdx.x * 4 + wv;
    float4 v = *(const float4*)(cb + (size_t)row * CDIM + lane * 4);
    float s = v.x * v.x + v.y * v.y + v.z * v.z + v.w * v.w;
    #pragma unroll
    for (int off = 32; off; off >>= 1) s += __shfl_down(s, off);
    if (lane == 0) cbnorm[row] = s;
    h4 hv = {(half_t)v.x, (half_t)v.y, (half_t)v.z, (half_t)v.w};
    *(h4*)(CBh + (size_t)row * CDIM + lane * 4) = hv;
}

// legacy cbnorm (fallback path only)
__global__ void k_cbnorm(const float* __restrict__ cb, float* __restrict__ cbnorm) {
    int wv = threadIdx.x >> 6, lane = threadIdx.x & 63;
    int row = blockIdx.x * 4 + wv;
    float4 v = *(const float4*)(cb + (size_t)row * CDIM + lane * 4);
    float s = v.x * v.x + v.y * v.y + v.z * v.z + v.w * v.w;
    #pragma unroll
    for (int off = 32; off; off >>= 1) s += __shfl_down(s, off);
    if (lane == 0) cbnorm[row] = s;
}

// ---------------- packed-key top-2 (branch-free) ----------------
// key = (order_bits(score) << 32) | col; u64 compare == lexicographic
// (score, col), i.e. argmin semantics incl. lowest-col tie-break.

__device__ __forceinline__ u64 pack_key(float s, int col) {
    unsigned b = __float_as_uint(s);
    unsigned o = b ^ (((unsigned)((int)b >> 31)) | 0x80000000u);  // monotone map
    return ((u64)o << 32) | (unsigned)col;
}
__device__ __forceinline__ u64 umin64(u64 a, u64 b) { return a < b ? a : b; }
__device__ __forceinline__ u64 umax64(u64 a, u64 b) { return a < b ? b : a; }

// scalar top-2 insert (fallback kernel only)
__device__ __forceinline__ void ins2(float v, int idx, float& b1, int& i1, float& b2, int& i2) {
    if (v < b1 || (v == b1 && idx < i1)) { b2 = b1; i2 = i1; b1 = v; i1 = idx; }
    else if (v < b2 || (v == b2 && idx < i2)) { b2 = v; i2 = idx; }
}

// ---------------- MFMA fp16 distance GEMM + per-split top-2 ----------------
// Round-19 = Round-17 verbatim (proven 61 us argmin / 74.9 us total, absmax 0).
// r18's double-buffer (2x barriers + stage-reg pressure) regressed to 68 us
// and is reverted; both structural pipelining levers (occupancy r14, dbuf r18)
// have now been measured to lose against this simple 2-barrier schedule.
#define MFMA16(a, b, c) __builtin_amdgcn_mfma_f32_16x16x32_f16(a, b, c, 0, 0, 0)
#define FOR8(M) M(0) M(1) M(2) M(3) M(4) M(5) M(6) M(7)

__launch_bounds__(256, 2)
__global__ void k_argmin_mfma(const float* __restrict__ X, const half_t* __restrict__ CBh,
                              const float* __restrict__ cbnorm,
                              u64* __restrict__ P1, u64* __restrict__ P2) {
    __shared__ __align__(16) half_t LBS[BN * CDIM];   // 64 KB

    const int tid = threadIdx.x;
    const int l = tid & 63, w = tid >> 6;              // 4 waves
    const int l15 = l & 15, g = l >> 4, l7 = l & 7;
    const int rowTile = blockIdx.x * BM;
    const int split = blockIdx.y;

    // ---- A prologue: 16 named h8 frags (2 bands x 8 ksteps), fp16(-2x) ----
    const float* xr0 = X + (size_t)(rowTile + w * 32 + l15) * CDIM + g * 8;
    const float* xr1 = xr0 + 16 * CDIM;
#define DECL_A(ks) h8 a0_##ks, a1_##ks;
    FOR8(DECL_A)
#undef DECL_A
#define LOADA(ks) { \
        float4 u0 = *(const float4*)(xr0 + (ks) * 32); \
        float4 u1 = *(const float4*)(xr0 + (ks) * 32 + 4); \
        a0_##ks = (h8){(half_t)(-2.f*u0.x), (half_t)(-2.f*u0.y), (half_t)(-2.f*u0.z), (half_t)(-2.f*u0.w), \
                       (half_t)(-2.f*u1.x), (half_t)(-2.f*u1.y), (half_t)(-2.f*u1.z), (half_t)(-2.f*u1.w)}; \
        float4 v0 = *(const float4*)(xr1 + (ks) * 32); \
        float4 v1 = *(const float4*)(xr1 + (ks) * 32 + 4); \
        a1_##ks = (h8){(half_t)(-2.f*v0.x), (half_t)(-2.f*v0.y), (half_t)(-2.f*v0.z), (half_t)(-2.f*v0.w), \
                       (half_t)(-2.f*v1.x), (half_t)(-2.f*v1.y), (half_t)(-2.f*v1.z), (half_t)(-2.f*v1.w)}; }
    FOR8(LOADA)
#undef LOADA

    // ---- top-2 state: 8 slots (2 bands x 4 regs) x 2 packed u64 ----
#define DECL_SLOT(s) u64 m1_##s = ~0ULL, m2_##s = ~0ULL;
    FOR8(DECL_SLOT)
#undef DECL_SLOT

#define DECL_ACC(fj) f32x4 cA##fj, cB##fj;
    FOR8(DECL_ACC)
#undef DECL_ACC

    for (int t = 0; t < TILES; ++t) {
        const int colBase = split * (O / NSPLIT) + t * BN;

        // ---- stage B tile: 16 x 16B fp16 copies/thread, swizzled write ----
        __syncthreads();   // previous tile's B reads drained
        #pragma unroll
        for (int p = 0; p < 16; ++p) {
            int chunk = p * 256 + tid;          // 0..4095
            int row = chunk >> 5;               // 0..127
            int cp = chunk & 31;                // LDS chunk slot
            int cs = cp ^ (row & 7);            // source chunk (both-sides XOR)
            *(h8*)(LBS + row * 256 + cp * 8) =
                *(const h8*)(CBh + (size_t)(colBase + row) * CDIM + cs * 8);
        }
        __syncthreads();   // B tile ready

        // acc init = ||c||^2 (col fixed per lane/frag)
#define INIT_ACC(fj) { \
            float cn_ = cbnorm[colBase + (fj) * 16 + l15]; \
            cA##fj = (f32x4){cn_, cn_, cn_, cn_}; \
            cB##fj = (f32x4){cn_, cn_, cn_, cn_}; }
        FOR8(INIT_ACC)
#undef INIT_ACC

        // ---- 8 K-steps, no barriers: A from regs, B from LDS ----
#define KSTEP(ks) { \
        const int koff = ((((ks) * 4 + g) ^ l7) * 8); \
        const half_t* bp = LBS + l15 * 256 + koff; \
        h8 b0 = *(const h8*)(bp + 0 * 4096); \
        h8 b1 = *(const h8*)(bp + 1 * 4096); \
        h8 b2 = *(const h8*)(bp + 2 * 4096); \
        h8 b3 = *(const h8*)(bp + 3 * 4096); \
        h8 b4 = *(const h8*)(bp + 4 * 4096); \
        h8 b5 = *(const h8*)(bp + 5 * 4096); \
        h8 b6 = *(const h8*)(bp + 6 * 4096); \
        h8 b7 = *(const h8*)(bp + 7 * 4096); \
        cA0 = MFMA16(a0_##ks, b0, cA0); cB0 = MFMA16(a1_##ks, b0, cB0); \
        cA1 = MFMA16(a0_##ks, b1, cA1); cB1 = MFMA16(a1_##ks, b1, cB1); \
        cA2 = MFMA16(a0_##ks, b2, cA2); cB2 = MFMA16(a1_##ks, b2, cB2); \
        cA3 = MFMA16(a0_##ks, b3, cA3); cB3 = MFMA16(a1_##ks, b3, cB3); \
        cA4 = MFMA16(a0_##ks, b4, cA4); cB4 = MFMA16(a1_##ks, b4, cB4); \
        cA5 = MFMA16(a0_##ks, b5, cA5); cB5 = MFMA16(a1_##ks, b5, cB5); \
        cA6 = MFMA16(a0_##ks, b6, cA6); cB6 = MFMA16(a1_##ks, b6, cB6); \
        cA7 = MFMA16(a0_##ks, b7, cA7); cB7 = MFMA16(a1_##ks, b7, cB7); }
        FOR8(KSTEP)
#undef KSTEP

        // ---- epilogue: branch-free packed top-2 insert (cn already in acc) --
#define INS(val, col, s) { \
            u64 k_ = pack_key((val), (col)); \
            u64 lo_ = umin64(m1_##s, k_); \
            u64 hi_ = umax64(m1_##s, k_); \
            m1_##s = lo_; m2_##s = umin64(m2_##s, hi_); }
#define EPI(fj) { \
            int col = colBase + (fj) * 16 + l15; \
            INS(cA##fj[0], col, 0) \
            INS(cA##fj[1], col, 1) \
            INS(cA##fj[2], col, 2) \
            INS(cA##fj[3], col, 3) \
            INS(cB##fj[0], col, 4) \
            INS(cB##fj[1], col, 5) \
            INS(cB##fj[2], col, 6) \
            INS(cB##fj[3], col, 7) }
        FOR8(EPI)
#undef EPI
#undef INS
    }

    // ---- butterfly across the 16 lanes sharing each output row ----
#define BFLY_STEP(s, m) { \
        u64 o1 = __shfl_xor(m1_##s, m); \
        u64 o2 = __shfl_xor(m2_##s, m); \
        u64 lo_ = umin64(m1_##s, o1); \
        u64 hi_ = umax64(m1_##s, o1); \
        m1_##s = lo_; \
        m2_##s = umin64(umin64(m2_##s, o2), hi_); }
#define BFLY(s) BFLY_STEP(s, 1) BFLY_STEP(s, 2) BFLY_STEP(s, 4) BFLY_STEP(s, 8)
    FOR8(BFLY)
#undef BFLY
#undef BFLY_STEP

#define STORE(s) if (l15 == (s)) { \
        int row = rowTile + w * 32 + ((s) >> 2) * 16 + g * 4 + ((s) & 3); \
        P1[row * NSPLIT + split] = m1_##s; \
        P2[row * NSPLIT + split] = m2_##s; }
    FOR8(STORE)
#undef STORE
}

// ---------------- f32 fallback (used only if ws too small) ------------------

__launch_bounds__(256, 2)
__global__ void k_argmin_f32(const float* __restrict__ X, const float* __restrict__ CB,
                             const float* __restrict__ cbnorm,
                             u64* __restrict__ P1, u64* __restrict__ P2) {
    __shared__ float LBUF[2 * 32 * (BM + 4)];
    float (*Fl)[BM + 4] = (float (*)[BM + 4])LBUF;
    float (*Cl)[BM + 4] = (float (*)[BM + 4])(LBUF + 32 * (BM + 4));

    const int tid = threadIdx.x;
    const int tx = tid & 15, ty = tid >> 4;
    const int rowTile = blockIdx.x * BM;
    const int split = blockIdx.y;
    const int lr = tid >> 3;
    const int lk = (tid & 7) * 4;

    float b1[8], b2[8];
    int i1[8], i2[8];
    #pragma unroll
    for (int i = 0; i < 8; ++i) { b1[i] = 3.4e38f; b2[i] = 3.4e38f; i1[i] = 0; i2[i] = 0; }

    for (int t = 0; t < TILES; ++t) {
        const int colBase = split * (O / NSPLIT) + t * BN;
        float acc[8][8];
        #pragma unroll
        for (int i = 0; i < 8; ++i)
            #pragma unroll
            for (int j = 0; j < 8; ++j) acc[i][j] = 0.0f;

        for (int k0 = 0; k0 < CDIM; k0 += 32) {
            __syncthreads();
            #pragma unroll
            for (int p = 0; p < 4; ++p) {
                int r = lr + p * 32;
                float4 v = *(const float4*)(X + (size_t)(rowTile + r) * CDIM + k0 + lk);
                Fl[lk + 0][r] = v.x; Fl[lk + 1][r] = v.y;
                Fl[lk + 2][r] = v.z; Fl[lk + 3][r] = v.w;
                float4 c = *(const float4*)(CB + (size_t)(colBase + r) * CDIM + k0 + lk);
                Cl[lk + 0][r] = c.x; Cl[lk + 1][r] = c.y;
                Cl[lk + 2][r] = c.z; Cl[lk + 3][r] = c.w;
            }
            __syncthreads();
            #pragma unroll
            for (int kk = 0; kk < 32; ++kk) {
                float4 a0 = *(const float4*)&Fl[kk][ty * 4];
                float4 a1 = *(const float4*)&Fl[kk][64 + ty * 4];
                float4 c0 = *(const float4*)&Cl[kk][tx * 4];
                float4 c1 = *(const float4*)&Cl[kk][64 + tx * 4];
                float a[8] = {a0.x, a0.y, a0.z, a0.w, a1.x, a1.y, a1.z, a1.w};
                float b[8] = {c0.x, c0.y, c0.z, c0.w, c1.x, c1.y, c1.z, c1.w};
                #pragma unroll
                for (int i = 0; i < 8; ++i)
                    #pragma unroll
                    for (int j = 0; j < 8; ++j)
                        acc[i][j] = fmaf(a[i], b[j], acc[i][j]);
            }
        }
        #pragma unroll
        for (int j = 0; j < 8; ++j) {
            int col = colBase + ((j < 4) ? (tx * 4 + j) : (64 + tx * 4 + (j - 4)));
            float cn = cbnorm[col];
            #pragma unroll
            for (int i = 0; i < 8; ++i) {
                float sc = fmaf(-2.0f, acc[i][j], cn);
                ins2(sc, col, b1[i], i1[i], b2[i], i2[i]);
            }
        }
    }

    __syncthreads();
    float* R1v = LBUF;
    int*   R1i = (int*)(LBUF + 2048);
    float* R2v = LBUF + 4096;
    int*   R2i = (int*)(LBUF + 6144);
    #pragma unroll
    for (int i = 0; i < 8; ++i) {
        int r = (i < 4) ? (ty * 4 + i) : (64 + ty * 4 + (i - 4));
        R1v[r * 16 + tx] = b1[i]; R1i[r * 16 + tx] = i1[i];
        R2v[r * 16 + tx] = b2[i]; R2i[r * 16 + tx] = i2[i];
    }
    __syncthreads();
    if (tid < BM) {
        float g1 = 3.4e38f, g2 = 3.4e38f; int gi1 = 0, gi2 = 0;
        #pragma unroll
        for (int x = 0; x < 16; ++x) {
            ins2(R1v[tid * 16 + x], R1i[tid * 16 + x], g1, gi1, g2, gi2);
            ins2(R2v[tid * 16 + x], R2i[tid * 16 + x], g1, gi1, g2, gi2);
        }
        int row = rowTile + tid;
        P1[row * NSPLIT + split] = pack_key(g1, gi1);
        P2[row * NSPLIT + split] = pack_key(g2, gi2);
    }
}

// -------- final: one wave per row. packed split-merge, f64 rescue (||x||^2
// cancels), inline threefry noise, gather, out write, combined loss partial.

__global__ void k_final(const float* __restrict__ X, const float* __restrict__ Y,
                        const float* __restrict__ CB,
                        const u64* __restrict__ P1, const u64* __restrict__ P2,
                        const unsigned* __restrict__ nstd,
                        float* __restrict__ out, float* __restrict__ s) {
    const int wv = threadIdx.x >> 6, lane = threadIdx.x & 63;
    const int row = blockIdx.x * 4 + wv;

    // merge NSPLIT packed top-2 pairs (branch-free, all lanes redundantly)
    u64 k1 = ~0ULL, k2 = ~0ULL;
    #pragma unroll
    for (int sp = 0; sp < NSPLIT; ++sp) {
        u64 q1 = P1[row * NSPLIT + sp];
        u64 q2 = P2[row * NSPLIT + sp];
        u64 lo = umin64(k1, q1);
        u64 hi = umax64(k1, q1);
        k1 = lo;
        k2 = umin64(umin64(k2, q2), hi);
    }
    int gi1 = (int)(k1 & 0xFFFFFFFFu);
    int gi2 = (int)(k2 & 0xFFFFFFFFu);

    const float4 xv = *(const float4*)(X + (size_t)row * CDIM + lane * 4);
    const float4 yv = *(const float4*)(Y + (size_t)row * CDIM + lane * 4);
    const float4 c1v = *(const float4*)(CB + (size_t)gi1 * CDIM + lane * 4);
    const float4 c2v = *(const float4*)(CB + (size_t)gi2 * CDIM + lane * 4);

    // f64 rescue: compare U = ||c||^2 - 2 x.c (||x||^2 cancels)
    double u1 = (double)c1v.x * ((double)c1v.x - 2.0 * (double)xv.x)
              + (double)c1v.y * ((double)c1v.y - 2.0 * (double)xv.y)
              + (double)c1v.z * ((double)c1v.z - 2.0 * (double)xv.z)
              + (double)c1v.w * ((double)c1v.w - 2.0 * (double)xv.w);
    double u2 = (double)c2v.x * ((double)c2v.x - 2.0 * (double)xv.x)
              + (double)c2v.y * ((double)c2v.y - 2.0 * (double)xv.y)
              + (double)c2v.z * ((double)c2v.z - 2.0 * (double)xv.z)
              + (double)c2v.w * ((double)c2v.w - 2.0 * (double)xv.w);
    #pragma unroll
    for (int m = 32; m; m >>= 1) {
        u1 += __shfl_xor(u1, m);
        u2 += __shfl_xor(u2, m);
    }
    int indDet = (u2 < u1 || (u2 == u1 && gi2 < gi1)) ? gi2 : gi1;
    int indNoisy = min(max(indDet + noise_for_row(row, nstd), 0), O - 1);

    float4 qd;
    qd.x = (indDet == gi1) ? c1v.x : c2v.x;
    qd.y = (indDet == gi1) ? c1v.y : c2v.y;
    qd.z = (indDet == gi1) ? c1v.z : c2v.z;
    qd.w = (indDet == gi1) ? c1v.w : c2v.w;
    const float4 qn = *(const float4*)(CB + (size_t)indNoisy * CDIM + lane * 4);

    float4 o;
    o.x = xv.x + (qn.x - xv.x);
    o.y = xv.y + (qn.y - xv.y);
    o.z = xv.z + (qn.z - xv.z);
    o.w = xv.w + (qn.w - xv.w);
    *(float4*)(out + (size_t)row * CDIM + lane * 4) = o;

    float e = 0.0f;
    {
        float d1, d2, d3;
        d1 = o.x - yv.x; d2 = xv.x - qd.x; d3 = qn.x - xv.x;
        e += d1 * d1 + 0.25f * (d2 * d2) + d3 * d3;
        d1 = o.y - yv.y; d2 = xv.y - qd.y; d3 = qn.y - xv.y;
        e += d1 * d1 + 0.25f * (d2 * d2) + d3 * d3;
        d1 = o.z - yv.z; d2 = xv.z - qd.z; d3 = qn.z - xv.z;
        e += d1 * d1 + 0.25f * (d2 * d2) + d3 * d3;
        d1 = o.w - yv.w; d2 = xv.w - qd.w; d3 = qn.w - xv.w;
        e += d1 * d1 + 0.25f * (d2 * d2) + d3 * d3;
    }
    #pragma unroll
    for (int m = 32; m; m >>= 1) e += __shfl_xor(e, m);
    if (lane == 0) s[row] = e;
}

__global__ void k_loss(const float* __restrict__ s, float* __restrict__ loss_out) {
    double a = 0.0;
    const float4* s4 = (const float4*)s;
    #pragma unroll
    for (int k = 0; k < 8; ++k) {
        float4 v = s4[threadIdx.x + k * 256];
        a += (double)v.x + (double)v.y + (double)v.z + (double)v.w;
    }
    #pragma unroll
    for (int off = 32; off; off >>= 1) a += __shfl_down(a, off);
    __shared__ double sh[4];
    int lane = threadIdx.x & 63, wv = threadIdx.x >> 6;
    if (lane == 0) sh[wv] = a;
    __syncthreads();
    if (threadIdx.x == 0) {
        double A = sh[0] + sh[1] + sh[2] + sh[3];
        loss_out[0] = (float)(A / ((double)Q * (double)CDIM));
    }
}

extern "C" void kernel_launch(void* const* d_in, const int* in_sizes, int n_in,
                              void* d_out, int out_size, void* d_ws, size_t ws_size,
                              hipStream_t stream) {
    int si = -1;
    const void* bigs[3] = {nullptr, nullptr, nullptr};
    int nb = 0;
    for (int i = 0; i < n_in; ++i) {
        if (in_sizes[i] == 1 && si < 0) si = i;
        else if (nb < 3) bigs[nb++] = d_in[i];
    }
    const float*    X    = (const float*)bigs[0];
    const float*    Y    = (const float*)bigs[1];
    const float*    CB   = (const float*)bigs[2];
    const unsigned* NSTD = (const unsigned*)(si >= 0 ? d_in[si] : d_in[n_in - 1]);
    float* out = (float*)d_out;

    float* ws = (float*)d_ws;
    float*  cbnorm = ws;                         // 8192 f32
    float*  s      = ws + 8192;                  // 8192 f32
    u64*    P1     = (u64*)(ws + 16384);         // 8192*8 u64 = 131072 f32-slots
    u64*    P2     = (u64*)(ws + 147456);        // 131072 f32-slots
    half_t* CBh    = (half_t*)(ws + 278528);     // 2M halfs = 4 MB
    const size_t WS_NEEDED = (size_t)(278528 + 1048576) * 4;  // 5,308,416 B

    if (ws_size >= WS_NEEDED) {
        hipLaunchKernelGGL(k_prep, dim3(O / 4), dim3(256), 0, stream, CB, cbnorm, CBh);
        hipLaunchKernelGGL(k_argmin_mfma, dim3(Q / BM, NSPLIT), dim3(256), 0, stream,
                           X, CBh, cbnorm, P1, P2);
    } else {
        hipLaunchKernelGGL(k_cbnorm, dim3(O / 4), dim3(256), 0, stream, CB, cbnorm);
        hipLaunchKernelGGL(k_argmin_f32, dim3(Q / BM, NSPLIT), dim3(256), 0, stream,
                           X, CB, cbnorm, P1, P2);
    }

    hipLaunchKernelGGL(k_final, dim3(Q / 4), dim3(256), 0, stream,
                       X, Y, CB, P1, P2, NSTD, out, s);
    hipLaunchKernelGGL(k_loss, dim3(1), dim3(256), 0, stream, s, out + (size_t)Q * CDIM);
}